// Round 1
// 268.423 us; speedup vs baseline: 1.0179x; 1.0179x over previous
//
#include <hip/hip_runtime.h>
#include <hip/hip_bf16.h>
#include <math.h>

#define NN 50000
#define EE 640000
#define DD 128
#define NREL 8
#define NCLS 16
#define NBUCK (NREL * NN)              // 400000 buckets, key = dst*8 + rel (dst-major)
#define SCAN_NB ((NBUCK + 255) / 256)  // 1563
#define NBIN 64
#define RECCAP 40                      // max cached recs/node in LDS (deg max ~34 at +6sigma)

typedef __attribute__((ext_vector_type(8))) short short8;   // 8 bf16 = 4 VGPRs
typedef __attribute__((ext_vector_type(4))) float f32x4;    // MFMA acc

__device__ __forceinline__ float bflo(unsigned u) { return __uint_as_float(u << 16); }
__device__ __forceinline__ float bfhi(unsigned u) { return __uint_as_float(u & 0xffff0000u); }
__device__ __forceinline__ float bf2f(ushort u) { return __uint_as_float(((unsigned)u) << 16); }
__device__ __forceinline__ ushort f2b(float f) {  // RNE
  unsigned u = __float_as_uint(f);
  u += 0x7fff + ((u >> 16) & 1);
  return (ushort)(u >> 16);
}

// ---------- CSR build (key = dst*8 + rel) ----------

__global__ __launch_bounds__(256) void count_kernel(const int* __restrict__ ei,
                                                    const int* __restrict__ et,
                                                    int* __restrict__ cnt) {
  int t = blockIdx.x * 256 + threadIdx.x;
  if (t < EE) {
    int key = ei[EE + t] * NREL + et[t];
    atomicAdd(&cnt[key], 1);
  }
}

__global__ __launch_bounds__(256) void scan1_kernel(const int* __restrict__ cnt,
                                                    int* __restrict__ off,
                                                    int* __restrict__ bsum) {
  __shared__ int s[256];
  const int tid = threadIdx.x;
  const int i = blockIdx.x * 256 + tid;
  int v = (i < NBUCK) ? cnt[i] : 0;
  s[tid] = v;
  __syncthreads();
#pragma unroll
  for (int o = 1; o < 256; o <<= 1) {
    int t2 = (tid >= o) ? s[tid - o] : 0;
    __syncthreads();
    s[tid] += t2;
    __syncthreads();
  }
  if (i < NBUCK) off[i] = s[tid] - v;
  if (tid == 255) bsum[blockIdx.x] = s[255];
}

__global__ __launch_bounds__(256) void scan2_kernel(const int* __restrict__ bsum,
                                                    int* __restrict__ bpre) {
  __shared__ int s[256];
  __shared__ int carry;
  const int tid = threadIdx.x;
  if (tid == 0) carry = 0;
  __syncthreads();
  const int chunks = (SCAN_NB + 255) / 256;
  for (int c = 0; c < chunks; c++) {
    int idx = c * 256 + tid;
    int v = (idx < SCAN_NB) ? bsum[idx] : 0;
    s[tid] = v;
    __syncthreads();
#pragma unroll
    for (int o = 1; o < 256; o <<= 1) {
      int t2 = (tid >= o) ? s[tid - o] : 0;
      __syncthreads();
      s[tid] += t2;
      __syncthreads();
    }
    if (idx < SCAN_NB) bpre[idx] = carry + s[tid] - v;
    __syncthreads();
    if (tid == 255) carry += s[255];
    __syncthreads();
  }
}

// finalizes off, fills cursor, zeroes the degree-bin histogram
__global__ __launch_bounds__(256) void scan3_kernel(int* __restrict__ off,
                                                    const int* __restrict__ bpre,
                                                    int* __restrict__ cursor,
                                                    int* __restrict__ hist) {
  int i = blockIdx.x * 256 + threadIdx.x;
  if (i < NBUCK) {
    int o = off[i] + bpre[i >> 8];
    off[i] = o;
    cursor[i] = o;
  }
  if (i < NBIN) hist[i] = 0;
  if (i == 0) off[NBUCK] = EE;
}

// rec word0 = src | rel<<16 ; word1 = ew/cnt (pre-divided mean scale)
__global__ __launch_bounds__(256) void bucket_kernel(const int* __restrict__ ei,
                                                     const int* __restrict__ et,
                                                     const float* __restrict__ ew,
                                                     const int* __restrict__ cnt,
                                                     int* __restrict__ cursor,
                                                     uint2* __restrict__ rec) {
  int e = blockIdx.x * 256 + threadIdx.x;
  if (e >= EE) return;
  int r = et[e];
  int key = ei[EE + e] * NREL + r;
  float scale = ew[e] / fmaxf((float)cnt[key], 1.0f);
  int pos = atomicAdd(&cursor[key], 1);
  rec[pos] = make_uint2((unsigned)ei[e] | ((unsigned)r << 16), __float_as_uint(scale));
}

// ---------- node-degree counting sort -> vqueue ----------

__global__ __launch_bounds__(256) void vhist_kernel(const int* __restrict__ off,
                                                    int* __restrict__ hist) {
  __shared__ int lh[NBIN];
  const int tid = threadIdx.x;
  if (tid < NBIN) lh[tid] = 0;
  __syncthreads();
  int v = blockIdx.x * 256 + tid;
  if (v < NN) {
    int deg = off[v * NREL + NREL] - off[v * NREL];
    atomicAdd(&lh[min(deg, NBIN - 1)], 1);
  }
  __syncthreads();
  if (tid < NBIN && lh[tid] > 0) atomicAdd(&hist[tid], lh[tid]);
}

__global__ __launch_bounds__(256) void scan64_kernel(const int* __restrict__ hist,
                                                     int* __restrict__ binCur) {
  __shared__ int s[NBIN];
  const int tid = threadIdx.x;
  if (tid < NBIN) s[tid] = hist[tid];
  __syncthreads();
#pragma unroll
  for (int o = 1; o < NBIN; o <<= 1) {
    int t2 = (tid < NBIN && tid >= o) ? s[tid - o] : 0;
    __syncthreads();
    if (tid < NBIN) s[tid] += t2;
    __syncthreads();
  }
  if (tid < NBIN) binCur[tid] = s[tid] - hist[tid];
}

__global__ __launch_bounds__(256) void vqbuild_kernel(const int* __restrict__ off,
                                                      int* __restrict__ binCur,
                                                      int* __restrict__ vqueue) {
  __shared__ int lh[NBIN];
  __shared__ int lbase[NBIN];
  const int tid = threadIdx.x;
  const int v = blockIdx.x * 256 + tid;
  int bin = -1, lpos = 0;
  if (tid < NBIN) lh[tid] = 0;
  __syncthreads();
  if (v < NN) {
    int deg = off[v * NREL + NREL] - off[v * NREL];
    bin = min(deg, NBIN - 1);
    lpos = atomicAdd(&lh[bin], 1);
  }
  __syncthreads();
  if (tid < NBIN && lh[tid] > 0) lbase[tid] = atomicAdd(&binCur[tid], lh[tid]);
  __syncthreads();
  if (bin >= 0) vqueue[lbase[bin] + lpos] = v;
}

// ---------- pack x (bf16) + W1Tc + W2T ----------
// W1Tc[n*1024 + r*128 + k] = bf16(W1[r][k][n]); W2T[j*128 + k] = bf16(W2[j>>4][k][j&15])
#define XQ (NN * DD / 4)
__global__ __launch_bounds__(256) void pack_kernel(const float* __restrict__ x,
                                                   const float* __restrict__ W1,
                                                   const float* __restrict__ W2,
                                                   ushort* __restrict__ xb,
                                                   ushort* __restrict__ W1Tc,
                                                   ushort* __restrict__ W2T) {
  int t = blockIdx.x * 256 + threadIdx.x;
  if (t < XQ) {
    float4 v = *(const float4*)&x[(size_t)t * 4];
    *(ushort4*)&xb[(size_t)t * 4] = make_ushort4(f2b(v.x), f2b(v.y), f2b(v.z), f2b(v.w));
  } else if (t < XQ + NREL * DD * DD) {
    int t2 = t - XQ;
    int n = t2 >> 10, r = (t2 >> 7) & 7, k = t2 & 127;
    W1Tc[t2] = f2b(W1[r * 16384 + k * 128 + n]);
  } else if (t < XQ + NREL * DD * DD + DD * DD) {
    int t2 = t - XQ - NREL * DD * DD;
    int j = t2 >> 7, k = t2 & 127;
    W2T[t2] = f2b(W2[(j >> 4) * (DD * NCLS) + k * NCLS + (j & 15)]);
  }
}

// ---------- fused layer1+layer2: H2 = bf16( relu(gather(x) @ W1cat) @ W2T^T ) ----------
// Block = 64 degree-sorted nodes (from vqueue) so the 8 nodes sharing a wave have
// near-equal degree -> wave gather trip count ~= mean, not max (kills exec-mask waste).
// Per-node rec ranges (contiguous, dst-major CSR) are preloaded into LDS with
// coalesced cooperative loads, removing the scattered rec load from the per-edge
// dependent chain (ds_read ~120cy vs global ~400cy). Global fallback for deg>RECCAP.
__global__ __launch_bounds__(512) void fused1_kernel(const int* __restrict__ off,
                                                     const uint2* __restrict__ rec,
                                                     const ushort* __restrict__ xb,
                                                     const ushort* __restrict__ W1Tc,
                                                     const ushort* __restrict__ W2T,
                                                     const int* __restrict__ vqueue,
                                                     ushort* __restrict__ H2) {
  __shared__ ushort AsU[64 * 136];         // 17408 B
  __shared__ uint2 recL[64 * RECCAP];      // 20480 B
  __shared__ int vids[64];                 // 256 B   (total 38144 B -> 4 blocks/CU)
  const int tid = threadIdx.x;
  const int m0 = blockIdx.x * 64;
  const int wave = tid >> 6, lane = tid & 63;
  const int lm = lane & 15, lkb = (lane >> 4) * 8;
  const int gn = tid >> 3;          // gather: node slot 0..63
  const int gj = tid & 7;           // gather: 8 threads/node
  const int gc = gj * 16;           // gather: col base (16 cols)
  const int qi = m0 + gn;
  const int v = (qi < NN) ? vqueue[qi] : -1;
  if (gj == 0) vids[gn] = v;

  // hoist the node's 9 contiguous offsets (dst-major key)
  int offv[9];
  if (v >= 0) {
    int4 o0 = *(const int4*)&off[v * 8];
    int4 o1 = *(const int4*)&off[v * 8 + 4];
    offv[0] = o0.x; offv[1] = o0.y; offv[2] = o0.z; offv[3] = o0.w;
    offv[4] = o1.x; offv[5] = o1.y; offv[6] = o1.z; offv[7] = o1.w;
    offv[8] = off[v * 8 + 8];
  } else {
#pragma unroll
    for (int i = 0; i < 9; i++) offv[i] = 0;
  }
  const int b0 = offv[0];
  const int rbase = gn * RECCAP;
  {
    int dcap = min(offv[8] - b0, RECCAP);
    for (int i = gj; i < dcap; i += 8) recL[rbase + i] = rec[b0 + i];
  }
  // recL visibility for r=0 is guaranteed by the r-loop's leading __syncthreads

#define GETREC(qdst, ii)                                        \
  do {                                                          \
    int _ri = (ii) - b0;                                        \
    if (_ri < RECCAP) qdst = recL[rbase + _ri];                 \
    else qdst = rec[(ii)];                                      \
  } while (0)

  f32x4 acc[4];
#pragma unroll
  for (int m = 0; m < 4; m++) acc[m] = (f32x4){0.f, 0.f, 0.f, 0.f};

#pragma unroll
  for (int r = 0; r < NREL; r++) {
    __syncthreads();  // previous chunk's AsU reads complete (and r=0: recL ready)
    // register gather, 2 edges in flight, 16 cols (2 uint4) per edge
    float g[16];
#pragma unroll
    for (int j = 0; j < 16; j++) g[j] = 0.f;
    {
      int s = offv[r], e = offv[r + 1];
      int i = s;
      for (; i + 2 <= e; i += 2) {
        uint2 q0, q1;
        GETREC(q0, i);
        GETREC(q1, i + 1);
        float sc0 = __uint_as_float(q0.y), sc1 = __uint_as_float(q1.y);
        const ushort* xr0 = &xb[(size_t)(q0.x & 0xffff) * DD + gc];
        const ushort* xr1 = &xb[(size_t)(q1.x & 0xffff) * DD + gc];
        uint4 h0[2], h1[2];
#pragma unroll
        for (int jj = 0; jj < 2; jj++) h0[jj] = *(const uint4*)&xr0[jj * 8];
#pragma unroll
        for (int jj = 0; jj < 2; jj++) h1[jj] = *(const uint4*)&xr1[jj * 8];
#pragma unroll
        for (int jj = 0; jj < 2; jj++) {
          float* gg = &g[jj * 8];
          gg[0] = fmaf(sc0, bflo(h0[jj].x), gg[0]);
          gg[1] = fmaf(sc0, bfhi(h0[jj].x), gg[1]);
          gg[2] = fmaf(sc0, bflo(h0[jj].y), gg[2]);
          gg[3] = fmaf(sc0, bfhi(h0[jj].y), gg[3]);
          gg[4] = fmaf(sc0, bflo(h0[jj].z), gg[4]);
          gg[5] = fmaf(sc0, bfhi(h0[jj].z), gg[5]);
          gg[6] = fmaf(sc0, bflo(h0[jj].w), gg[6]);
          gg[7] = fmaf(sc0, bfhi(h0[jj].w), gg[7]);
          gg[0] = fmaf(sc1, bflo(h1[jj].x), gg[0]);
          gg[1] = fmaf(sc1, bfhi(h1[jj].x), gg[1]);
          gg[2] = fmaf(sc1, bflo(h1[jj].y), gg[2]);
          gg[3] = fmaf(sc1, bfhi(h1[jj].y), gg[3]);
          gg[4] = fmaf(sc1, bflo(h1[jj].z), gg[4]);
          gg[5] = fmaf(sc1, bfhi(h1[jj].z), gg[5]);
          gg[6] = fmaf(sc1, bflo(h1[jj].w), gg[6]);
          gg[7] = fmaf(sc1, bfhi(h1[jj].w), gg[7]);
        }
      }
      if (i < e) {
        uint2 q;
        GETREC(q, i);
        float sc = __uint_as_float(q.y);
        const ushort* xr = &xb[(size_t)(q.x & 0xffff) * DD + gc];
#pragma unroll
        for (int jj = 0; jj < 2; jj++) {
          uint4 h = *(const uint4*)&xr[jj * 8];
          float* gg = &g[jj * 8];
          gg[0] = fmaf(sc, bflo(h.x), gg[0]);
          gg[1] = fmaf(sc, bfhi(h.x), gg[1]);
          gg[2] = fmaf(sc, bflo(h.y), gg[2]);
          gg[3] = fmaf(sc, bfhi(h.y), gg[3]);
          gg[4] = fmaf(sc, bflo(h.z), gg[4]);
          gg[5] = fmaf(sc, bfhi(h.z), gg[5]);
          gg[6] = fmaf(sc, bflo(h.w), gg[6]);
          gg[7] = fmaf(sc, bfhi(h.w), gg[7]);
        }
      }
    }
#pragma unroll
    for (int jj = 0; jj < 2; jj++) {
      uint4 u;
      u.x = (unsigned)f2b(g[jj * 8 + 0]) | ((unsigned)f2b(g[jj * 8 + 1]) << 16);
      u.y = (unsigned)f2b(g[jj * 8 + 2]) | ((unsigned)f2b(g[jj * 8 + 3]) << 16);
      u.z = (unsigned)f2b(g[jj * 8 + 4]) | ((unsigned)f2b(g[jj * 8 + 5]) << 16);
      u.w = (unsigned)f2b(g[jj * 8 + 6]) | ((unsigned)f2b(g[jj * 8 + 7]) << 16);
      *(uint4*)&AsU[gn * 136 + gc + jj * 8] = u;
    }
    __syncthreads();
    // MFMA: wave owns out-cols [wave*16, wave*16+16); B fragment from L2
#pragma unroll
    for (int k0 = 0; k0 < 128; k0 += 32) {
      short8 b = *(const short8*)&W1Tc[(size_t)(wave * 16 + lm) * 1024 + r * 128 + k0 + lkb];
      short8 a[4];
#pragma unroll
      for (int m = 0; m < 4; m++)
        a[m] = *(const short8*)&AsU[(m * 16 + lm) * 136 + k0 + lkb];
#pragma unroll
      for (int m = 0; m < 4; m++)
        acc[m] = __builtin_amdgcn_mfma_f32_16x16x32_bf16(a[m], b, acc[m], 0, 0, 0);
    }
  }
#undef GETREC

  // ---- epilogue 1: relu -> bf16 A2 tile in LDS ----
  __syncthreads();
  const int rquad = (lane >> 4) * 4;
#pragma unroll
  for (int m = 0; m < 4; m++)
#pragma unroll
    for (int i = 0; i < 4; i++)
      AsU[(m * 16 + rquad + i) * 136 + wave * 16 + lm] = f2b(fmaxf(acc[m][i], 0.f));
  __syncthreads();

  // ---- layer-2 GEMM on the in-LDS A2 tile (W2T from L2) ----
  f32x4 acc2[4];
#pragma unroll
  for (int m = 0; m < 4; m++) acc2[m] = (f32x4){0.f, 0.f, 0.f, 0.f};
#pragma unroll
  for (int k0 = 0; k0 < 128; k0 += 32) {
    short8 b = *(const short8*)&W2T[(size_t)(wave * 16 + lm) * DD + k0 + lkb];
    short8 a[4];
#pragma unroll
    for (int m = 0; m < 4; m++)
      a[m] = *(const short8*)&AsU[(m * 16 + lm) * 136 + k0 + lkb];
#pragma unroll
    for (int m = 0; m < 4; m++)
      acc2[m] = __builtin_amdgcn_mfma_f32_16x16x32_bf16(a[m], b, acc2[m], 0, 0, 0);
  }
  __syncthreads();
#pragma unroll
  for (int m = 0; m < 4; m++)
#pragma unroll
    for (int i = 0; i < 4; i++)
      AsU[(m * 16 + rquad + i) * 136 + wave * 16 + lm] = f2b(acc2[m][i]);
  __syncthreads();
#pragma unroll
  for (int i = 0; i < 2; i++) {
    int seg = tid + i * 512;
    int row = seg >> 4, c8 = (seg & 15) * 8;
    int gr = vids[row];
    if (gr >= 0) *(uint4*)&H2[(size_t)gr * DD + c8] = *(const uint4*)&AsU[row * 136 + c8];
  }
}

// ---------- gather2 + log_softmax ----------
// 16 nodes/block from degree-sorted queue; 16 lanes/node walk the node's single
// contiguous edge range (rel tag in rec), 2 edges in flight; rec range preloaded
// into LDS (coalesced) to shorten the rec->H2 dependent chain; fused log-softmax.
__global__ __launch_bounds__(256) void gather2_kernel(const int* __restrict__ off,
                                                      const uint2* __restrict__ rec,
                                                      const ushort* __restrict__ H2,
                                                      const int* __restrict__ vqueue,
                                                      float* __restrict__ out) {
  __shared__ uint2 recL[16 * RECCAP];  // 5120 B
  const int tid = threadIdx.x;
  const int g = tid >> 4, c = tid & 15;
  const int qi = blockIdx.x * 16 + g;
  int v = 0, s = 0, e = 0;
  if (qi < NN) {
    v = vqueue[qi];
    s = off[v * NREL];
    e = off[v * NREL + NREL];
  }
  const int rbase = g * RECCAP;
  {
    int dcap = min(e - s, RECCAP);
    for (int i = c; i < dcap; i += 16) recL[rbase + i] = rec[s + i];
  }
  __syncthreads();

#define GETREC2(qdst, ii)                                       \
  do {                                                          \
    int _ri = (ii) - s;                                         \
    if (_ri < RECCAP) qdst = recL[rbase + _ri];                 \
    else qdst = rec[(ii)];                                      \
  } while (0)

  float acc = 0.f;
  if (qi < NN) {
    int j = s;
    for (; j + 2 <= e; j += 2) {
      uint2 q0, q1;
      GETREC2(q0, j);
      GETREC2(q1, j + 1);
      ushort h0 = H2[(size_t)(q0.x & 0xffff) * DD + (q0.x >> 16) * NCLS + c];
      ushort h1 = H2[(size_t)(q1.x & 0xffff) * DD + (q1.x >> 16) * NCLS + c];
      acc = fmaf(__uint_as_float(q0.y), bf2f(h0), acc);
      acc = fmaf(__uint_as_float(q1.y), bf2f(h1), acc);
    }
    if (j < e) {
      uint2 q;
      GETREC2(q, j);
      acc = fmaf(__uint_as_float(q.y),
                 bf2f(H2[(size_t)(q.x & 0xffff) * DD + (q.x >> 16) * NCLS + c]), acc);
    }
  }
#undef GETREC2
  float m = acc;
#pragma unroll
  for (int mask = 8; mask >= 1; mask >>= 1) m = fmaxf(m, __shfl_xor(m, mask, 16));
  float ex = expf(acc - m);
#pragma unroll
  for (int mask = 8; mask >= 1; mask >>= 1) ex += __shfl_xor(ex, mask, 16);
  if (qi < NN) out[(size_t)v * NCLS + c] = acc - m - logf(ex);
}

extern "C" void kernel_launch(void* const* d_in, const int* in_sizes, int n_in,
                              void* d_out, int out_size, void* d_ws, size_t ws_size,
                              hipStream_t stream) {
  const float* x  = (const float*)d_in[0];
  const int*   ei = (const int*)d_in[1];
  const int*   et = (const int*)d_in[2];
  const float* ew = (const float*)d_in[3];
  const float* W1 = (const float*)d_in[4];
  const float* W2 = (const float*)d_in[5];
  float* out = (float*)d_out;
  float* ws = (float*)d_ws;

  // workspace layout (float-unit offsets; ~36 MB)
  int*    cnt    = (int*)ws;                    // 400000
  int*    off    = (int*)(ws + 400000);         // 400001 (+pad)
  int*    bsum   = (int*)(ws + 800004);         // 1563 (+pad)
  int*    bpre   = (int*)(ws + 801568);         // 1563 (+pad)
  int*    cursor = (int*)(ws + 803132);         // 400000
  int*    hist   = (int*)(ws + 1203132);        // 64
  int*    binCur = (int*)(ws + 1203196);        // 64
  int*    vqueue = (int*)(ws + 1203260);        // 50000
  uint2*  rec    = (uint2*)(ws + 1253260);      // 640000 uint2
  ushort* xb     = (ushort*)(ws + 2533260);     // NN*DD bf16
  ushort* W1Tc   = (ushort*)(ws + 5733260);     // 128*1024 bf16
  ushort* W2T    = (ushort*)(ws + 5798796);     // 128*128 bf16
  ushort* H2     = (ushort*)(ws + 5806988);     // NN*DD bf16

  hipMemsetAsync(cnt, 0, (size_t)NBUCK * sizeof(int), stream);

  count_kernel<<<(EE + 255) / 256, 256, 0, stream>>>(ei, et, cnt);
  scan1_kernel<<<SCAN_NB, 256, 0, stream>>>(cnt, off, bsum);
  scan2_kernel<<<1, 256, 0, stream>>>(bsum, bpre);
  scan3_kernel<<<SCAN_NB, 256, 0, stream>>>(off, bpre, cursor, hist);
  bucket_kernel<<<(EE + 255) / 256, 256, 0, stream>>>(ei, et, ew, cnt, cursor, rec);

  vhist_kernel<<<(NN + 255) / 256, 256, 0, stream>>>(off, hist);
  scan64_kernel<<<1, 256, 0, stream>>>(hist, binCur);
  vqbuild_kernel<<<(NN + 255) / 256, 256, 0, stream>>>(off, binCur, vqueue);

  const int packN = XQ + NREL * DD * DD + DD * DD;
  pack_kernel<<<(packN + 255) / 256, 256, 0, stream>>>(x, W1, W2, xb, W1Tc, W2T);

  fused1_kernel<<<(NN + 63) / 64, 512, 0, stream>>>(off, rec, xb, W1Tc, W2T, vqueue, H2);
  gather2_kernel<<<(NN + 15) / 16, 256, 0, stream>>>(off, rec, H2, vqueue, out);
}